// Round 10
// baseline (29.676 us; speedup 1.0000x reference)
//
#include <hip/hip_runtime.h>
#include <math.h>

#define Gg 64
#define Ll 4096
#define Ss 65536
#define Nn (Gg * Ll)                      // 262144 rows
#define PB 1024                           // pair-block threads
#define CHUNKS 4                          // blocks per group (1 block/CU)
#define PAIR_BLOCKS (Gg * CHUNKS)         // 256 = one per CU
#define PPB (Ss / CHUNKS)                 // 16384 pairs per block (16/thread)
#define BLOCK 256

// fallback path constants
#define K_CHUNKS 32
#define DIR_BLOCKS (Gg * K_CHUNKS)
#define DIR_PAIRS (Ss / K_CHUNKS)

typedef _Float16 h2 __attribute__((ext_vector_type(2)));
typedef _Float16 h4 __attribute__((ext_vector_type(4)));

struct f3 { float x, y, z; };             // align 4, size 12 -> dwordx3 load

__device__ inline float dot2f16(h2 a, h2 b, float c) {
#if __has_builtin(__builtin_amdgcn_fdot2)
  return __builtin_amdgcn_fdot2(a, b, c, false);
#else
  return fmaf((float)a[0], (float)b[0], fmaf((float)a[1], (float)b[1], c));
#endif
}

// ---------------------------------------------------------------------------
// Fused kernel (int32 indices), hybrid dual-pipe gather.
// 12/16 pairs per thread gather via LDS (DS pipe, fp16 SoA2 tile as round 9);
// 4/16 pairs gather DIRECTLY from the raw f32 arrays (TA/vector-mem pipe,
// 4 x dwordx3 per pair, L2-resident: 8 groups x 288KB = 2.3MB per XCD).
// The two pipes are independent; G-loads are issued 2-pairs-deep ahead of
// the LDS batches so DS and TA traffic overlap within each wave.
// ---------------------------------------------------------------------------
__global__ __launch_bounds__(PB, 4) void fused_kernel(
    const float* __restrict__ inp, const float* __restrict__ tgt,
    const int* __restrict__ left, const int* __restrict__ right,
    float* __restrict__ partial) {
  __shared__ h4 tileA[Ll];   // (in.x,in.y,tg.x,tg.y)  32 KB
  __shared__ h2 tileC[Ll];   // (in.z,tg.z)            16 KB

  int bid = blockIdx.x;
  int xcd = bid & 7;
  int j = bid >> 3;                // [0,32)
  int group = xcd * 8 + (j & 7);   // all 4 chunk-blocks of a group on one XCD
  int chunk = j >> 3;              // [0,4)
  int tid = threadIdx.x;

  // ---- phase 1: stage + compact, 4 rows per thread ----
  const float* ib = inp + (size_t)group * Ll * 9 + 3;  // CA atom base
  const float* tb = tgt + (size_t)group * Ll * 9 + 3;
#pragma unroll
  for (int q = 0; q < 4; ++q) {
    int row = q * PB + tid;
    f3 a = *(const f3*)(ib + (size_t)row * 9);
    f3 b = *(const f3*)(tb + (size_t)row * 9);
    h4 va;
    va[0] = (_Float16)a.x; va[1] = (_Float16)a.y;
    va[2] = (_Float16)b.x; va[3] = (_Float16)b.y;
    h2 vc;
    vc[0] = (_Float16)a.z; vc[1] = (_Float16)b.z;
    tileA[row] = va;
    tileC[row] = vc;
  }
  __syncthreads();

  // ---- phase 2: hybrid gather, 16 pairs/thread ----
  size_t base = (size_t)group * Ss + (size_t)chunk * PPB;
  const int4* lp = (const int4*)(left + base);
  const int4* rp = (const int4*)(right + base);

  // G-batch indices first (their gathers issue earliest)
  int4 L3 = lp[3 * PB + tid];
  int4 R3 = rp[3 * PB + tid];
  int4 L0 = lp[0 * PB + tid];
  int4 R0 = rp[0 * PB + tid];
  int4 L1 = lp[1 * PB + tid];
  int4 R1 = rp[1 * PB + tid];
  int4 L2 = lp[2 * PB + tid];
  int4 R2 = rp[2 * PB + tid];

  float facc = 0.f;

  // raw f32 CA row load (global row id -> TA pipe)
#define G_LOAD(gid, vi, vt)                                       \
  f3 vi = *(const f3*)(inp + (size_t)(unsigned)(gid) * 9 + 3);    \
  f3 vt = *(const f3*)(tgt + (size_t)(unsigned)(gid) * 9 + 3);

#define G_MATH(li_, lt_, ri_, rt_)                                \
  do {                                                            \
    float dx = li_.x - ri_.x, dy = li_.y - ri_.y, dz = li_.z - ri_.z; \
    float tx = lt_.x - rt_.x, ty = lt_.y - rt_.y, tz = lt_.z - rt_.z; \
    float din = sqrtf(fmaf(dx, dx, fmaf(dy, dy, dz * dz)));       \
    float dtg = sqrtf(fmaf(tx, tx, fmaf(ty, ty, tz * tz)));       \
    float dd = din - dtg;                                         \
    facc = fmaf(dd, dd, facc);                                    \
  } while (0)

#define PAIR_STEP(LI, RI)                                        \
  do {                                                           \
    int li = (LI) & (Ll - 1);                                    \
    int ri = (RI) & (Ll - 1);                                    \
    h4 dA = tileA[li] - tileA[ri];                               \
    h2 dC = tileC[li] - tileC[ri];                               \
    h2 dxy_in = __builtin_shufflevector(dA, dA, 0, 1);           \
    h2 dxy_tg = __builtin_shufflevector(dA, dA, 2, 3);           \
    float dzi = (float)dC[0];                                    \
    float dzt = (float)dC[1];                                    \
    float din2 = dot2f16(dxy_in, dxy_in, dzi * dzi);             \
    float dtg2 = dot2f16(dxy_tg, dxy_tg, dzt * dzt);             \
    float dd = sqrtf(din2) - sqrtf(dtg2);                        \
    facc = fmaf(dd, dd, facc);                                   \
  } while (0)

  // --- G group A in flight (pairs L3.x, L3.y): 8 dwordx3 loads ---
  G_LOAD(L3.x, gAli, gAlt) G_LOAD(R3.x, gAri, gArt)
  G_LOAD(L3.y, gBli, gBlt) G_LOAD(R3.y, gBri, gBrt)

  // LDS batch 0+1 (8 pairs) overlap the in-flight G loads
  PAIR_STEP(L0.x, R0.x); PAIR_STEP(L0.y, R0.y);
  PAIR_STEP(L0.z, R0.z); PAIR_STEP(L0.w, R0.w);
  PAIR_STEP(L1.x, R1.x); PAIR_STEP(L1.y, R1.y);
  PAIR_STEP(L1.z, R1.z); PAIR_STEP(L1.w, R1.w);

  // consume G group A; issue G group B (pairs L3.z, L3.w)
  G_MATH(gAli, gAlt, gAri, gArt);
  G_MATH(gBli, gBlt, gBri, gBrt);
  G_LOAD(L3.z, gCli, gClt) G_LOAD(R3.z, gCri, gCrt)
  G_LOAD(L3.w, gDli, gDlt) G_LOAD(R3.w, gDri, gDrt)

  // LDS batch 2 (4 pairs) overlap G group B
  PAIR_STEP(L2.x, R2.x); PAIR_STEP(L2.y, R2.y);
  PAIR_STEP(L2.z, R2.z); PAIR_STEP(L2.w, R2.w);

  // consume G group B
  G_MATH(gCli, gClt, gCri, gCrt);
  G_MATH(gDli, gDlt, gDri, gDrt);

#undef PAIR_STEP
#undef G_LOAD
#undef G_MATH

  // ---- block reduce -> partial ----
  for (int off = 32; off; off >>= 1) facc += __shfl_down(facc, off, 64);
  __shared__ float wsum[PB / 64];
  int lane = tid & 63;
  int wave = tid >> 6;
  if (lane == 0) wsum[wave] = facc;
  __syncthreads();
  if (tid == 0) {
    float s = 0.f;
    for (int w = 0; w < PB / 64; ++w) s += wsum[w];
    partial[bid] = s;
  }
}

// ---------------------------------------------------------------------------
// Fallback (int64 indices or tiny workspace): direct f32 gathers.
// ---------------------------------------------------------------------------
template <typename IT>
__global__ __launch_bounds__(BLOCK) void pair_kernel_direct(
    const float* __restrict__ inp, const float* __restrict__ tgt,
    const IT* __restrict__ left, const IT* __restrict__ right,
    float* __restrict__ partial) {
  int bid = blockIdx.x;
  int x = bid & 7;
  int j = bid >> 3;
  int group = x + 8 * (j / K_CHUNKS);
  int chunk = j % K_CHUNKS;
  size_t base = (size_t)group * Ss + (size_t)chunk * DIR_PAIRS;

  float acc = 0.f;
  for (int t = threadIdx.x; t < DIR_PAIRS; t += BLOCK) {
    size_t p = base + t;
    size_t li = (size_t)left[p] * 9 + 3;
    size_t ri = (size_t)right[p] * 9 + 3;
    float dx = inp[li + 0] - inp[ri + 0];
    float dy = inp[li + 1] - inp[ri + 1];
    float dz = inp[li + 2] - inp[ri + 2];
    float tx = tgt[li + 0] - tgt[ri + 0];
    float ty = tgt[li + 1] - tgt[ri + 1];
    float tz = tgt[li + 2] - tgt[ri + 2];
    float din = sqrtf(dx * dx + dy * dy + dz * dz);
    float dtg = sqrtf(tx * tx + ty * ty + tz * tz);
    float d = din - dtg;
    acc += d * d;
  }
  for (int off = 32; off; off >>= 1) acc += __shfl_down(acc, off, 64);
  __shared__ float wsum[BLOCK / 64];
  if ((threadIdx.x & 63) == 0) wsum[threadIdx.x >> 6] = acc;
  __syncthreads();
  if (threadIdx.x == 0) {
    float s = 0.f;
    for (int w = 0; w < BLOCK / 64; ++w) s += wsum[w];
    partial[bid] = s;
  }
}

// ---------------------------------------------------------------------------
// Final reduce: deterministic fixed-order fp64 sum of block partials.
// ---------------------------------------------------------------------------
__global__ __launch_bounds__(BLOCK) void reduce_kernel(
    const float* __restrict__ partial, int n, float* __restrict__ out) {
  double acc = 0.0;
  for (int i = threadIdx.x; i < n; i += BLOCK) acc += (double)partial[i];
  for (int off = 32; off; off >>= 1) acc += __shfl_down(acc, off, 64);
  __shared__ double wsum[BLOCK / 64];
  if ((threadIdx.x & 63) == 0) wsum[threadIdx.x >> 6] = acc;
  __syncthreads();
  if (threadIdx.x == 0) {
    double s = 0.0;
    for (int w = 0; w < BLOCK / 64; ++w) s += wsum[w];
    out[0] = (float)(s / (double)((size_t)Gg * Ss));
  }
}

extern "C" void kernel_launch(void* const* d_in, const int* in_sizes, int n_in,
                              void* d_out, int out_size, void* d_ws, size_t ws_size,
                              hipStream_t stream) {
  const float* inp = (const float*)d_in[0];   // (N,3,3) f32
  const float* tgt = (const float*)d_in[1];   // (N,3,3) f32
  // d_in[2] = mask (unused by the reference)
  const void* leftp = d_in[3];
  const void* rightp = d_in[4];
  float* out = (float*)d_out;

  const int P = Gg * Ss;                       // 4194304
  const bool idx64 = (in_sizes[3] == 2 * P);   // int64 passthrough guard

  size_t partBytes = (size_t)DIR_BLOCKS * sizeof(float);

  if (!idx64 && ws_size >= partBytes) {
    float* partial = (float*)d_ws;
    fused_kernel<<<PAIR_BLOCKS, PB, 0, stream>>>(
        inp, tgt, (const int*)leftp, (const int*)rightp, partial);
    reduce_kernel<<<1, BLOCK, 0, stream>>>(partial, PAIR_BLOCKS, out);
  } else {
    float* partial = (float*)d_ws;
    if (idx64) {
      pair_kernel_direct<long long><<<DIR_BLOCKS, BLOCK, 0, stream>>>(
          inp, tgt, (const long long*)leftp, (const long long*)rightp, partial);
    } else {
      pair_kernel_direct<int><<<DIR_BLOCKS, BLOCK, 0, stream>>>(
          inp, tgt, (const int*)leftp, (const int*)rightp, partial);
    }
    reduce_kernel<<<1, BLOCK, 0, stream>>>(partial, DIR_BLOCKS, out);
  }
}

// Round 11
// 29.595 us; speedup vs baseline: 1.0027x; 1.0027x over previous
//
#include <hip/hip_runtime.h>
#include <math.h>

#define Gg 64
#define Ll 4096
#define Ss 65536
#define Nn (Gg * Ll)                      // 262144 rows
#define PB 1024                           // pair-block threads
#define CHUNKS 4                          // blocks per group (1 block/CU)
#define PAIR_BLOCKS (Gg * CHUNKS)         // 256 = one per CU
#define PPB (Ss / CHUNKS)                 // 16384 pairs per block (16/thread)
#define BLOCK 256

// fallback path constants
#define K_CHUNKS 32
#define DIR_BLOCKS (Gg * K_CHUNKS)
#define DIR_PAIRS (Ss / K_CHUNKS)

typedef _Float16 h2 __attribute__((ext_vector_type(2)));
typedef _Float16 h4 __attribute__((ext_vector_type(4)));

struct f3 { float x, y, z; };             // align 4, size 12 -> dwordx3 load

__device__ inline float dot2f16(h2 a, h2 b, float c) {
#if __has_builtin(__builtin_amdgcn_fdot2)
  return __builtin_amdgcn_fdot2(a, b, c, false);
#else
  return fmaf((float)a[0], (float)b[0], fmaf((float)a[1], (float)b[1], c));
#endif
}

// ---------------------------------------------------------------------------
// Fused kernel (int32 indices), hybrid dual-pipe gather.
// 12/16 pairs per thread gather via LDS (DS pipe, fp16 SoA2 tile as round 9);
// 4/16 pairs gather DIRECTLY from the raw f32 arrays (TA/vector-mem pipe,
// 4 x dwordx3 per pair, L2-resident: 8 groups x 288KB = 2.3MB per XCD).
// The two pipes are independent; G-loads are issued 2-pairs-deep ahead of
// the LDS batches so DS and TA traffic overlap within each wave.
// ---------------------------------------------------------------------------
__global__ __launch_bounds__(PB, 4) void fused_kernel(
    const float* __restrict__ inp, const float* __restrict__ tgt,
    const int* __restrict__ left, const int* __restrict__ right,
    float* __restrict__ partial) {
  __shared__ h4 tileA[Ll];   // (in.x,in.y,tg.x,tg.y)  32 KB
  __shared__ h2 tileC[Ll];   // (in.z,tg.z)            16 KB

  int bid = blockIdx.x;
  int xcd = bid & 7;
  int j = bid >> 3;                // [0,32)
  int group = xcd * 8 + (j & 7);   // all 4 chunk-blocks of a group on one XCD
  int chunk = j >> 3;              // [0,4)
  int tid = threadIdx.x;

  // ---- phase 1: stage + compact, 4 rows per thread ----
  const float* ib = inp + (size_t)group * Ll * 9 + 3;  // CA atom base
  const float* tb = tgt + (size_t)group * Ll * 9 + 3;
#pragma unroll
  for (int q = 0; q < 4; ++q) {
    int row = q * PB + tid;
    f3 a = *(const f3*)(ib + (size_t)row * 9);
    f3 b = *(const f3*)(tb + (size_t)row * 9);
    h4 va;
    va[0] = (_Float16)a.x; va[1] = (_Float16)a.y;
    va[2] = (_Float16)b.x; va[3] = (_Float16)b.y;
    h2 vc;
    vc[0] = (_Float16)a.z; vc[1] = (_Float16)b.z;
    tileA[row] = va;
    tileC[row] = vc;
  }
  __syncthreads();

  // ---- phase 2: hybrid gather, 16 pairs/thread ----
  size_t base = (size_t)group * Ss + (size_t)chunk * PPB;
  const int4* lp = (const int4*)(left + base);
  const int4* rp = (const int4*)(right + base);

  // G-batch indices first (their gathers issue earliest)
  int4 L3 = lp[3 * PB + tid];
  int4 R3 = rp[3 * PB + tid];
  int4 L0 = lp[0 * PB + tid];
  int4 R0 = rp[0 * PB + tid];
  int4 L1 = lp[1 * PB + tid];
  int4 R1 = rp[1 * PB + tid];
  int4 L2 = lp[2 * PB + tid];
  int4 R2 = rp[2 * PB + tid];

  float facc = 0.f;

  // raw f32 CA row load (global row id -> TA pipe)
#define G_LOAD(gid, vi, vt)                                       \
  f3 vi = *(const f3*)(inp + (size_t)(unsigned)(gid) * 9 + 3);    \
  f3 vt = *(const f3*)(tgt + (size_t)(unsigned)(gid) * 9 + 3);

#define G_MATH(li_, lt_, ri_, rt_)                                \
  do {                                                            \
    float dx = li_.x - ri_.x, dy = li_.y - ri_.y, dz = li_.z - ri_.z; \
    float tx = lt_.x - rt_.x, ty = lt_.y - rt_.y, tz = lt_.z - rt_.z; \
    float din = sqrtf(fmaf(dx, dx, fmaf(dy, dy, dz * dz)));       \
    float dtg = sqrtf(fmaf(tx, tx, fmaf(ty, ty, tz * tz)));       \
    float dd = din - dtg;                                         \
    facc = fmaf(dd, dd, facc);                                    \
  } while (0)

#define PAIR_STEP(LI, RI)                                        \
  do {                                                           \
    int li = (LI) & (Ll - 1);                                    \
    int ri = (RI) & (Ll - 1);                                    \
    h4 dA = tileA[li] - tileA[ri];                               \
    h2 dC = tileC[li] - tileC[ri];                               \
    h2 dxy_in = __builtin_shufflevector(dA, dA, 0, 1);           \
    h2 dxy_tg = __builtin_shufflevector(dA, dA, 2, 3);           \
    float dzi = (float)dC[0];                                    \
    float dzt = (float)dC[1];                                    \
    float din2 = dot2f16(dxy_in, dxy_in, dzi * dzi);             \
    float dtg2 = dot2f16(dxy_tg, dxy_tg, dzt * dzt);             \
    float dd = sqrtf(din2) - sqrtf(dtg2);                        \
    facc = fmaf(dd, dd, facc);                                   \
  } while (0)

  // --- G group A in flight (pairs L3.x, L3.y): 8 dwordx3 loads ---
  G_LOAD(L3.x, gAli, gAlt) G_LOAD(R3.x, gAri, gArt)
  G_LOAD(L3.y, gBli, gBlt) G_LOAD(R3.y, gBri, gBrt)

  // LDS batch 0+1 (8 pairs) overlap the in-flight G loads
  PAIR_STEP(L0.x, R0.x); PAIR_STEP(L0.y, R0.y);
  PAIR_STEP(L0.z, R0.z); PAIR_STEP(L0.w, R0.w);
  PAIR_STEP(L1.x, R1.x); PAIR_STEP(L1.y, R1.y);
  PAIR_STEP(L1.z, R1.z); PAIR_STEP(L1.w, R1.w);

  // consume G group A; issue G group B (pairs L3.z, L3.w)
  G_MATH(gAli, gAlt, gAri, gArt);
  G_MATH(gBli, gBlt, gBri, gBrt);
  G_LOAD(L3.z, gCli, gClt) G_LOAD(R3.z, gCri, gCrt)
  G_LOAD(L3.w, gDli, gDlt) G_LOAD(R3.w, gDri, gDrt)

  // LDS batch 2 (4 pairs) overlap G group B
  PAIR_STEP(L2.x, R2.x); PAIR_STEP(L2.y, R2.y);
  PAIR_STEP(L2.z, R2.z); PAIR_STEP(L2.w, R2.w);

  // consume G group B
  G_MATH(gCli, gClt, gCri, gCrt);
  G_MATH(gDli, gDlt, gDri, gDrt);

#undef PAIR_STEP
#undef G_LOAD
#undef G_MATH

  // ---- block reduce -> partial ----
  for (int off = 32; off; off >>= 1) facc += __shfl_down(facc, off, 64);
  __shared__ float wsum[PB / 64];
  int lane = tid & 63;
  int wave = tid >> 6;
  if (lane == 0) wsum[wave] = facc;
  __syncthreads();
  if (tid == 0) {
    float s = 0.f;
    for (int w = 0; w < PB / 64; ++w) s += wsum[w];
    partial[bid] = s;
  }
}

// ---------------------------------------------------------------------------
// Fallback (int64 indices or tiny workspace): direct f32 gathers.
// ---------------------------------------------------------------------------
template <typename IT>
__global__ __launch_bounds__(BLOCK) void pair_kernel_direct(
    const float* __restrict__ inp, const float* __restrict__ tgt,
    const IT* __restrict__ left, const IT* __restrict__ right,
    float* __restrict__ partial) {
  int bid = blockIdx.x;
  int x = bid & 7;
  int j = bid >> 3;
  int group = x + 8 * (j / K_CHUNKS);
  int chunk = j % K_CHUNKS;
  size_t base = (size_t)group * Ss + (size_t)chunk * DIR_PAIRS;

  float acc = 0.f;
  for (int t = threadIdx.x; t < DIR_PAIRS; t += BLOCK) {
    size_t p = base + t;
    size_t li = (size_t)left[p] * 9 + 3;
    size_t ri = (size_t)right[p] * 9 + 3;
    float dx = inp[li + 0] - inp[ri + 0];
    float dy = inp[li + 1] - inp[ri + 1];
    float dz = inp[li + 2] - inp[ri + 2];
    float tx = tgt[li + 0] - tgt[ri + 0];
    float ty = tgt[li + 1] - tgt[ri + 1];
    float tz = tgt[li + 2] - tgt[ri + 2];
    float din = sqrtf(dx * dx + dy * dy + dz * dz);
    float dtg = sqrtf(tx * tx + ty * ty + tz * tz);
    float d = din - dtg;
    acc += d * d;
  }
  for (int off = 32; off; off >>= 1) acc += __shfl_down(acc, off, 64);
  __shared__ float wsum[BLOCK / 64];
  if ((threadIdx.x & 63) == 0) wsum[threadIdx.x >> 6] = acc;
  __syncthreads();
  if (threadIdx.x == 0) {
    float s = 0.f;
    for (int w = 0; w < BLOCK / 64; ++w) s += wsum[w];
    partial[bid] = s;
  }
}

// ---------------------------------------------------------------------------
// Final reduce: deterministic fixed-order fp64 sum of block partials.
// ---------------------------------------------------------------------------
__global__ __launch_bounds__(BLOCK) void reduce_kernel(
    const float* __restrict__ partial, int n, float* __restrict__ out) {
  double acc = 0.0;
  for (int i = threadIdx.x; i < n; i += BLOCK) acc += (double)partial[i];
  for (int off = 32; off; off >>= 1) acc += __shfl_down(acc, off, 64);
  __shared__ double wsum[BLOCK / 64];
  if ((threadIdx.x & 63) == 0) wsum[threadIdx.x >> 6] = acc;
  __syncthreads();
  if (threadIdx.x == 0) {
    double s = 0.0;
    for (int w = 0; w < BLOCK / 64; ++w) s += wsum[w];
    out[0] = (float)(s / (double)((size_t)Gg * Ss));
  }
}

extern "C" void kernel_launch(void* const* d_in, const int* in_sizes, int n_in,
                              void* d_out, int out_size, void* d_ws, size_t ws_size,
                              hipStream_t stream) {
  const float* inp = (const float*)d_in[0];   // (N,3,3) f32
  const float* tgt = (const float*)d_in[1];   // (N,3,3) f32
  // d_in[2] = mask (unused by the reference)
  const void* leftp = d_in[3];
  const void* rightp = d_in[4];
  float* out = (float*)d_out;

  const int P = Gg * Ss;                       // 4194304
  const bool idx64 = (in_sizes[3] == 2 * P);   // int64 passthrough guard

  size_t partBytes = (size_t)DIR_BLOCKS * sizeof(float);

  if (!idx64 && ws_size >= partBytes) {
    float* partial = (float*)d_ws;
    fused_kernel<<<PAIR_BLOCKS, PB, 0, stream>>>(
        inp, tgt, (const int*)leftp, (const int*)rightp, partial);
    reduce_kernel<<<1, BLOCK, 0, stream>>>(partial, PAIR_BLOCKS, out);
  } else {
    float* partial = (float*)d_ws;
    if (idx64) {
      pair_kernel_direct<long long><<<DIR_BLOCKS, BLOCK, 0, stream>>>(
          inp, tgt, (const long long*)leftp, (const long long*)rightp, partial);
    } else {
      pair_kernel_direct<int><<<DIR_BLOCKS, BLOCK, 0, stream>>>(
          inp, tgt, (const int*)leftp, (const int*)rightp, partial);
    }
    reduce_kernel<<<1, BLOCK, 0, stream>>>(partial, DIR_BLOCKS, out);
  }
}

// Round 12
// 19.203 us; speedup vs baseline: 1.5454x; 1.5412x over previous
//
#include <hip/hip_runtime.h>
#include <math.h>

#define Gg 64
#define Ll 4096
#define Ss 65536
#define Nn (Gg * Ll)                      // 262144 rows
#define PB 1024                           // pair-block threads
#define CHUNKS 8                          // blocks per group
#define PAIR_BLOCKS (Gg * CHUNKS)         // 512
#define PPB (Ss / CHUNKS)                 // 8192 pairs per block (8/thread)
#define BLOCK 256

// fallback path constants
#define K_CHUNKS 32
#define DIR_BLOCKS (Gg * K_CHUNKS)
#define DIR_PAIRS (Ss / K_CHUNKS)

typedef _Float16 h2 __attribute__((ext_vector_type(2)));
typedef _Float16 h8 __attribute__((ext_vector_type(8)));

struct f3 { float x, y, z; };             // align 4, size 12 -> dwordx3 load

__device__ inline float dot2f16(h2 a, h2 b, float c) {
#if __has_builtin(__builtin_amdgcn_fdot2)
  return __builtin_amdgcn_fdot2(a, b, c, false);
#else
  return fmaf((float)a[0], (float)b[0], fmaf((float)a[1], (float)b[1], c));
#endif
}

// gather one pair from the LDS tile
#define PAIR_STEP(LI, RI)                                        \
  do {                                                           \
    h8 Lv = tile[(LI) & (Ll - 1)];                               \
    h8 Rv = tile[(RI) & (Ll - 1)];                               \
    h8 Dv = Lv - Rv;                                             \
    h2 d01 = __builtin_shufflevector(Dv, Dv, 0, 1);              \
    h2 d23 = __builtin_shufflevector(Dv, Dv, 2, 3);              \
    float dzi = (float)Dv[4];                                    \
    float dzt = (float)Dv[5];                                    \
    float din2 = dot2f16(d01, d01, dzi * dzi);                   \
    float dtg2 = dot2f16(d23, d23, dzt * dzt);                   \
    float dd = sqrtf(din2) - sqrtf(dtg2);                        \
    facc = fmaf(dd, dd, facc);                                   \
  } while (0)

// ---------------------------------------------------------------------------
// Fused kernel (int32 indices) — round-6 configuration (best measured:
// 19.15us). Per block: compact the group's 4096 raw CA rows to fp16 in LDS,
// then gather 8192 pairs from LDS. XCD-aware block->group mapping keeps all
// 8 chunk-blocks of a group on one XCD (raw-row re-reads are L2-served).
// __launch_bounds__(PB, 8): VGPR<=64 so 2 blocks/CU (32 waves) co-reside.
// All index vectors prefetched upfront.
// ---------------------------------------------------------------------------
__global__ __launch_bounds__(PB, 8) void fused_kernel(
    const float* __restrict__ inp, const float* __restrict__ tgt,
    const int* __restrict__ left, const int* __restrict__ right,
    float* __restrict__ partial) {
  __shared__ h8 tile[Ll];   // 64 KB

  int bid = blockIdx.x;
  int xcd = bid & 7;
  int j = bid >> 3;
  int group = xcd * 8 + (j & 7);  // all 8 chunk-blocks of a group on one XCD
  int chunk = j >> 3;
  int tid = threadIdx.x;

  // ---- prefetch ALL indices ----
  size_t base = (size_t)group * Ss + (size_t)chunk * PPB;
  const int4* lp = (const int4*)(left + base);
  const int4* rp = (const int4*)(right + base);
  int4 L0 = lp[tid];
  int4 R0 = rp[tid];
  int4 L1 = lp[PB + tid];
  int4 R1 = rp[PB + tid];

  // ---- stage + compact: 4 rows per thread ----
  const float* ib = inp + (size_t)group * Ll * 9 + 3;  // CA atom base
  const float* tb = tgt + (size_t)group * Ll * 9 + 3;
#pragma unroll
  for (int q = 0; q < 4; ++q) {
    int row = q * PB + tid;
    f3 a = *(const f3*)(ib + (size_t)row * 9);
    f3 b = *(const f3*)(tb + (size_t)row * 9);
    h8 r;
    r[0] = (_Float16)a.x;
    r[1] = (_Float16)a.y;
    r[2] = (_Float16)b.x;
    r[3] = (_Float16)b.y;
    r[4] = (_Float16)a.z;
    r[5] = (_Float16)b.z;
    r[6] = (_Float16)0.f;
    r[7] = (_Float16)0.f;
    tile[row] = r;
  }
  __syncthreads();

  // ---- gather: 8 pairs/thread, pure LDS + VALU ----
  float facc = 0.f;
  PAIR_STEP(L0.x, R0.x);
  PAIR_STEP(L0.y, R0.y);
  PAIR_STEP(L0.z, R0.z);
  PAIR_STEP(L0.w, R0.w);
  PAIR_STEP(L1.x, R1.x);
  PAIR_STEP(L1.y, R1.y);
  PAIR_STEP(L1.z, R1.z);
  PAIR_STEP(L1.w, R1.w);

  // ---- block reduce -> partial ----
  for (int off = 32; off; off >>= 1) facc += __shfl_down(facc, off, 64);
  __shared__ float wsum[PB / 64];
  int lane = tid & 63;
  int wave = tid >> 6;
  if (lane == 0) wsum[wave] = facc;
  __syncthreads();
  if (tid == 0) {
    float s = 0.f;
    for (int w = 0; w < PB / 64; ++w) s += wsum[w];
    partial[bid] = s;
  }
}

// ---------------------------------------------------------------------------
// Fallback (int64 indices or tiny workspace): direct f32 gathers.
// ---------------------------------------------------------------------------
template <typename IT>
__global__ __launch_bounds__(BLOCK) void pair_kernel_direct(
    const float* __restrict__ inp, const float* __restrict__ tgt,
    const IT* __restrict__ left, const IT* __restrict__ right,
    float* __restrict__ partial) {
  int bid = blockIdx.x;
  int x = bid & 7;
  int j = bid >> 3;
  int group = x + 8 * (j / K_CHUNKS);
  int chunk = j % K_CHUNKS;
  size_t base = (size_t)group * Ss + (size_t)chunk * DIR_PAIRS;

  float acc = 0.f;
  for (int t = threadIdx.x; t < DIR_PAIRS; t += BLOCK) {
    size_t p = base + t;
    size_t li = (size_t)left[p] * 9 + 3;
    size_t ri = (size_t)right[p] * 9 + 3;
    float dx = inp[li + 0] - inp[ri + 0];
    float dy = inp[li + 1] - inp[ri + 1];
    float dz = inp[li + 2] - inp[ri + 2];
    float tx = tgt[li + 0] - tgt[ri + 0];
    float ty = tgt[li + 1] - tgt[ri + 1];
    float tz = tgt[li + 2] - tgt[ri + 2];
    float din = sqrtf(dx * dx + dy * dy + dz * dz);
    float dtg = sqrtf(tx * tx + ty * ty + tz * tz);
    float d = din - dtg;
    acc += d * d;
  }
  for (int off = 32; off; off >>= 1) acc += __shfl_down(acc, off, 64);
  __shared__ float wsum[BLOCK / 64];
  if ((threadIdx.x & 63) == 0) wsum[threadIdx.x >> 6] = acc;
  __syncthreads();
  if (threadIdx.x == 0) {
    float s = 0.f;
    for (int w = 0; w < BLOCK / 64; ++w) s += wsum[w];
    partial[bid] = s;
  }
}

// ---------------------------------------------------------------------------
// Final reduce: deterministic fixed-order fp64 sum of block partials.
// ---------------------------------------------------------------------------
__global__ __launch_bounds__(BLOCK) void reduce_kernel(
    const float* __restrict__ partial, int n, float* __restrict__ out) {
  double acc = 0.0;
  for (int i = threadIdx.x; i < n; i += BLOCK) acc += (double)partial[i];
  for (int off = 32; off; off >>= 1) acc += __shfl_down(acc, off, 64);
  __shared__ double wsum[BLOCK / 64];
  if ((threadIdx.x & 63) == 0) wsum[threadIdx.x >> 6] = acc;
  __syncthreads();
  if (threadIdx.x == 0) {
    double s = 0.0;
    for (int w = 0; w < BLOCK / 64; ++w) s += wsum[w];
    out[0] = (float)(s / (double)((size_t)Gg * Ss));
  }
}

extern "C" void kernel_launch(void* const* d_in, const int* in_sizes, int n_in,
                              void* d_out, int out_size, void* d_ws, size_t ws_size,
                              hipStream_t stream) {
  const float* inp = (const float*)d_in[0];   // (N,3,3) f32
  const float* tgt = (const float*)d_in[1];   // (N,3,3) f32
  // d_in[2] = mask (unused by the reference)
  const void* leftp = d_in[3];
  const void* rightp = d_in[4];
  float* out = (float*)d_out;

  const int P = Gg * Ss;                       // 4194304
  const bool idx64 = (in_sizes[3] == 2 * P);   // int64 passthrough guard

  size_t partBytes = (size_t)DIR_BLOCKS * sizeof(float);

  if (!idx64 && ws_size >= partBytes) {
    float* partial = (float*)d_ws;
    fused_kernel<<<PAIR_BLOCKS, PB, 0, stream>>>(
        inp, tgt, (const int*)leftp, (const int*)rightp, partial);
    reduce_kernel<<<1, BLOCK, 0, stream>>>(partial, PAIR_BLOCKS, out);
  } else {
    float* partial = (float*)d_ws;
    if (idx64) {
      pair_kernel_direct<long long><<<DIR_BLOCKS, BLOCK, 0, stream>>>(
          inp, tgt, (const long long*)leftp, (const long long*)rightp, partial);
    } else {
      pair_kernel_direct<int><<<DIR_BLOCKS, BLOCK, 0, stream>>>(
          inp, tgt, (const int*)leftp, (const int*)rightp, partial);
    }
    reduce_kernel<<<1, BLOCK, 0, stream>>>(partial, DIR_BLOCKS, out);
  }
}